// Round 1
// baseline (352.850 us; speedup 1.0000x reference)
//
#include <hip/hip_runtime.h>
#include <math.h>

#define B_    4
#define T_    8192
#define C_    1024
#define E_    64
#define NTOK  (B_*T_)          // 32768
#define KSEL  2

// d_out offsets (in floats): idx, scores, probs, importance, load
#define OFF_IDX    0
#define OFF_SCORES (NTOK*KSEL)               // 65536
#define OFF_PROBS  (2*NTOK*KSEL)             // 131072
#define OFF_IMP    (OFF_PROBS + NTOK*E_)     // 2228224
#define OFF_LOAD   (OFF_IMP + E_)            // 2228288

// workspace offsets (bytes)
#define WS_WCOMB64 0                          // 1024*64*8 = 524288
#define WS_HCOND64 524288                     // 4*1024*8  = 32768
#define WS_LBIAS64 557056                     // 4*64*8    = 2048
#define WS_WCOMB32 559104                     // 1024*64*4 = 262144
#define WS_LBIAS32 821248                     // 4*64*4    = 1024
#define WS_CNT     822272                     // 4
#define WS_LIST    822784                     // REFINE_CAP*4

#define REFINE_CAP 4096
#define REFINE_EPS 3e-4f

// ---------------------------------------------------------------------------
// K1: Wcomb[d][e] = sum_c Wc[c][d] * Wg[e][c]   (fp64 accumulate)
// grid 256 blocks x 256 threads; block handles d = blk*4 .. blk*4+3, all e.
// ---------------------------------------------------------------------------
__global__ __launch_bounds__(256) void k_wcomb(const float* __restrict__ Wg,
                                               const float* __restrict__ Wc,
                                               double* __restrict__ wcomb64,
                                               float* __restrict__ wcomb32) {
    __shared__ float wg_s[64 * 65];   // [e][c] padded
    __shared__ float wc_s[64 * 4];    // [c][dl]
    const int tid = threadIdx.x;
    const int e  = tid & 63;
    const int dl = tid >> 6;                  // 0..3 (uniform per wave)
    const int d  = blockIdx.x * 4 + dl;

    double acc = 0.0;
    for (int c0 = 0; c0 < C_; c0 += 64) {
        __syncthreads();
#pragma unroll
        for (int k = 0; k < 16; ++k) {
            int li = tid + k * 256;
            int el = li >> 6, cc = li & 63;
            wg_s[el * 65 + cc] = Wg[el * 1024 + c0 + cc];
        }
        {
            int cc = tid >> 2, dd = tid & 3;
            wc_s[cc * 4 + dd] = Wc[(size_t)(c0 + cc) * 2048 + blockIdx.x * 4 + dd];
        }
        __syncthreads();
#pragma unroll 4
        for (int cc = 0; cc < 64; ++cc) {
            acc += (double)wc_s[cc * 4 + dl] * (double)wg_s[e * 65 + cc];
        }
    }
    wcomb64[d * 64 + e] = acc;
    wcomb32[d * 64 + e] = (float)acc;
}

// ---------------------------------------------------------------------------
// K2: hcond64[b][c] = sum_d cond[b][d] * Wc[c][1024+d]  (fp64)
// one wave per (b,c) output; 1024 blocks x 256 threads = 4096 waves.
// ---------------------------------------------------------------------------
__global__ __launch_bounds__(256) void k_hcond(const float* __restrict__ cond,
                                               const float* __restrict__ Wc,
                                               double* __restrict__ hcond64) {
    int wave = (int)((blockIdx.x * blockDim.x + threadIdx.x) >> 6);  // 0..4095
    int lane = threadIdx.x & 63;
    int b = wave >> 10;
    int c = wave & 1023;
    const float* wrow = Wc + (size_t)c * 2048 + 1024;
    const float* crow = cond + b * 1024;
    double acc = 0.0;
#pragma unroll 4
    for (int d = lane; d < 1024; d += 64)
        acc += (double)crow[d] * (double)wrow[d];
    for (int off = 32; off > 0; off >>= 1)
        acc += __shfl_down(acc, off, 64);
    if (lane == 0) hcond64[b * 1024 + c] = acc;
}

// ---------------------------------------------------------------------------
// K3: lbias64[b][e] = sum_c hcond64[b][c] * Wg[e][c]  (fp64)
// one wave per (b,e); 64 blocks x 256 threads = 256 waves.
// ---------------------------------------------------------------------------
__global__ __launch_bounds__(256) void k_lbias(const double* __restrict__ hcond64,
                                               const float* __restrict__ Wg,
                                               double* __restrict__ lbias64,
                                               float* __restrict__ lbias32) {
    int wave = (int)((blockIdx.x * blockDim.x + threadIdx.x) >> 6);  // 0..255
    int lane = threadIdx.x & 63;
    int b = wave >> 6;
    int e = wave & 63;
    double acc = 0.0;
#pragma unroll 4
    for (int c = lane; c < 1024; c += 64)
        acc += hcond64[b * 1024 + c] * (double)Wg[e * 1024 + c];
    for (int off = 32; off > 0; off >>= 1)
        acc += __shfl_down(acc, off, 64);
    if (lane == 0) { lbias64[b * 64 + e] = acc; lbias32[b * 64 + e] = (float)acc; }
}

// ---------------------------------------------------------------------------
// K_main: logits = x @ Wcomb + lbias[b]; softmax; top-2; stats.
// 512 blocks x 256 threads; 64 tokens x 64 experts per block.
// thread tile: 4 tokens x 4 experts. m_t = tid&15, e_t = tid>>4.
// ---------------------------------------------------------------------------
#define MT   64
#define XPAD 68   // pad: bank (4*tok + j) % 32 -> conflict-free b128 reads

__global__ __launch_bounds__(256) void k_main(const float* __restrict__ x,
                                              const float* __restrict__ wcomb32,
                                              const float* __restrict__ lbias32,
                                              float* __restrict__ out,
                                              unsigned int* __restrict__ ref_cnt,
                                              int* __restrict__ ref_list) {
    __shared__ float xs[MT * XPAD];     // x tile; reused for logits/exp tile
    __shared__ float wsm[64 * 64];      // Wcomb chunk [j][e]
    __shared__ float invs[MT];
    __shared__ unsigned int cnts[E_];

    const int tid = threadIdx.x;
    const int m_t = tid & 15;           // token group
    const int e_t = tid >> 4;           // expert group 0..15
    const int token0 = blockIdx.x * MT;
    const int b = token0 / T_;          // blocks never straddle a batch

    if (tid < E_) cnts[tid] = 0;

    float4 acc[4];
#pragma unroll
    for (int i = 0; i < 4; ++i) acc[i] = make_float4(0.f, 0.f, 0.f, 0.f);

    for (int d0 = 0; d0 < C_; d0 += 64) {
        __syncthreads();
        // stage x tile: 64 tokens x 64 d  (coalesced float4)
#pragma unroll
        for (int k = 0; k < 4; ++k) {
            int li = tid + k * 256;            // 0..1023 float4 index
            int r = li >> 4, c4 = (li & 15) << 2;
            float4 v = *(const float4*)&x[(size_t)(token0 + r) * C_ + d0 + c4];
            *(float4*)&xs[r * XPAD + c4] = v;
        }
        // stage Wcomb chunk: contiguous 4096 floats
#pragma unroll
        for (int k = 0; k < 4; ++k) {
            int li = tid + k * 256;
            float4 v = *(const float4*)&wcomb32[(size_t)d0 * 64 + (size_t)li * 4];
            *(float4*)&wsm[li * 4] = v;
        }
        __syncthreads();
#pragma unroll 2
        for (int j = 0; j < 64; j += 4) {
            float4 w0 = *(const float4*)&wsm[(j + 0) * 64 + e_t * 4];
            float4 w1 = *(const float4*)&wsm[(j + 1) * 64 + e_t * 4];
            float4 w2 = *(const float4*)&wsm[(j + 2) * 64 + e_t * 4];
            float4 w3 = *(const float4*)&wsm[(j + 3) * 64 + e_t * 4];
#pragma unroll
            for (int i = 0; i < 4; ++i) {
                float4 xv = *(const float4*)&xs[(m_t + 16 * i) * XPAD + j];
                acc[i].x += xv.x * w0.x; acc[i].y += xv.x * w0.y;
                acc[i].z += xv.x * w0.z; acc[i].w += xv.x * w0.w;
                acc[i].x += xv.y * w1.x; acc[i].y += xv.y * w1.y;
                acc[i].z += xv.y * w1.z; acc[i].w += xv.y * w1.w;
                acc[i].x += xv.z * w2.x; acc[i].y += xv.z * w2.y;
                acc[i].z += xv.z * w2.z; acc[i].w += xv.z * w2.w;
                acc[i].x += xv.w * w3.x; acc[i].y += xv.w * w3.y;
                acc[i].z += xv.w * w3.z; acc[i].w += xv.w * w3.w;
            }
        }
    }

    // epilogue: add lbias, write logits into xs tile
    __syncthreads();
    float4 lb = *(const float4*)&lbias32[b * 64 + e_t * 4];
#pragma unroll
    for (int i = 0; i < 4; ++i) {
        int tok = m_t + 16 * i;
        float4 v = make_float4(acc[i].x + lb.x, acc[i].y + lb.y,
                               acc[i].z + lb.z, acc[i].w + lb.w);
        *(float4*)&xs[tok * XPAD + e_t * 4] = v;
    }
    __syncthreads();

    if (tid < MT) {
        const int t = tid;
        float v1 = -1e30f, v2 = -1e30f, v3 = -1e30f;
        int i1 = 0, i2 = 0;
        for (int e = 0; e < E_; ++e) {
            float l = xs[t * XPAD + e];
            if (l > v1)      { v3 = v2; v2 = v1; i2 = i1; v1 = l; i1 = e; }
            else if (l > v2) { v3 = v2; v2 = l; i2 = e; }
            else if (l > v3) { v3 = l; }
        }
        float sum = 0.f;
        for (int e = 0; e < E_; ++e) {
            float ex = __expf(xs[t * XPAD + e] - v1);
            xs[t * XPAD + e] = ex;
            sum += ex;
        }
        invs[t] = 1.0f / sum;

        const int gt = token0 + t;
        float s1 = 1.0f / (1.0f + __expf(v2 - v1));   // softmax over top-2
        *(float2*)&out[OFF_IDX + (size_t)gt * 2]    = make_float2((float)i1, (float)i2);
        *(float2*)&out[OFF_SCORES + (size_t)gt * 2] = make_float2(s1, 1.0f - s1);
        atomicAdd(&cnts[i1], 1u);
        atomicAdd(&cnts[i2], 1u);

        float g12 = v1 - v2, g23 = v2 - v3;
        float g = g12 < g23 ? g12 : g23;
        if (g < REFINE_EPS) {
            unsigned int pos = atomicAdd(ref_cnt, 1u);
            if (pos < REFINE_CAP) ref_list[pos] = gt;
        }
    }
    __syncthreads();

    // probs: 4096 floats, coalesced float4
    float* probs = out + OFF_PROBS + (size_t)token0 * E_;
#pragma unroll
    for (int k = 0; k < 4; ++k) {
        int li4 = tid + k * 256;                 // float4 index 0..1023
        int tok = li4 >> 4;
        int c4 = (li4 & 15) << 2;
        float4 ex = *(const float4*)&xs[tok * XPAD + c4];
        float inv = invs[tok];
        *(float4*)&probs[(size_t)li4 * 4] =
            make_float4(ex.x * inv, ex.y * inv, ex.z * inv, ex.w * inv);
    }

    // importance (mean of probs) + load (counts/65536): one atomic each per e
    if (tid < E_) {
        const int e = tid;
        float s = 0.f;
        for (int t = 0; t < MT; ++t) s += xs[t * XPAD + e] * invs[t];
        atomicAdd(&out[OFF_IMP + e],  s * (1.0f / (float)NTOK));
        atomicAdd(&out[OFF_LOAD + e], (float)cnts[e] * (1.0f / (float)(NTOK * KSEL)));
    }
}

// ---------------------------------------------------------------------------
// K_ref: fp64 re-evaluation of ambiguous tokens (near-tie top-2/top-3 gaps).
// One wave per flagged token; lane = expert.
// ---------------------------------------------------------------------------
__global__ __launch_bounds__(256) void k_refine(const float* __restrict__ x,
                                                const double* __restrict__ wcomb64,
                                                const double* __restrict__ lbias64,
                                                const unsigned int* __restrict__ ref_cnt,
                                                const int* __restrict__ ref_list,
                                                float* __restrict__ out) {
    int wave = (int)((blockIdx.x * blockDim.x + threadIdx.x) >> 6);
    int lane = threadIdx.x & 63;
    unsigned int n = *ref_cnt;
    if (n > REFINE_CAP) n = REFINE_CAP;
    const int nwaves = (int)((gridDim.x * blockDim.x) >> 6);

    for (unsigned int wi = wave; wi < n; wi += nwaves) {
        const int gt = ref_list[wi];
        const int b = gt / T_;
        const float* xrow = x + (size_t)gt * C_;
        double acc = lbias64[b * 64 + lane];
#pragma unroll 4
        for (int d = 0; d < C_; ++d)
            acc += (double)xrow[d] * wcomb64[d * 64 + lane];

        // top-1 (tie -> lower index)
        double v = acc; int id = lane;
        for (int off = 32; off > 0; off >>= 1) {
            double ov = __shfl_xor(v, off, 64);
            int oid   = __shfl_xor(id, off, 64);
            if (ov > v || (ov == v && oid < id)) { v = ov; id = oid; }
        }
        double v1 = v; int i1 = id;
        // top-2
        v = (lane == i1) ? -1e300 : acc; id = lane;
        for (int off = 32; off > 0; off >>= 1) {
            double ov = __shfl_xor(v, off, 64);
            int oid   = __shfl_xor(id, off, 64);
            if (ov > v || (ov == v && oid < id)) { v = ov; id = oid; }
        }
        double v2 = v; int i2 = id;

        if (lane == 0) {
            float s1 = (float)(1.0 / (1.0 + exp(v2 - v1)));
            *(float2*)&out[OFF_IDX + (size_t)gt * 2]    = make_float2((float)i1, (float)i2);
            *(float2*)&out[OFF_SCORES + (size_t)gt * 2] = make_float2(s1, 1.0f - s1);
        }
    }
}

// ---------------------------------------------------------------------------
extern "C" void kernel_launch(void* const* d_in, const int* in_sizes, int n_in,
                              void* d_out, int out_size, void* d_ws, size_t ws_size,
                              hipStream_t stream) {
    const float* x    = (const float*)d_in[0];   // (4,8192,1024)
    const float* cond = (const float*)d_in[1];   // (4,1024)
    const float* Wg   = (const float*)d_in[2];   // (64,1024)
    const float* Wc   = (const float*)d_in[3];   // (1024,2048)
    float* out = (float*)d_out;
    char*  ws  = (char*)d_ws;

    double* wcomb64 = (double*)(ws + WS_WCOMB64);
    double* hcond64 = (double*)(ws + WS_HCOND64);
    double* lbias64 = (double*)(ws + WS_LBIAS64);
    float*  wcomb32 = (float*)(ws + WS_WCOMB32);
    float*  lbias32 = (float*)(ws + WS_LBIAS32);
    unsigned int* ref_cnt = (unsigned int*)(ws + WS_CNT);
    int*    ref_list = (int*)(ws + WS_LIST);

    hipMemsetAsync(ref_cnt, 0, 4, stream);
    hipMemsetAsync(out + OFF_IMP, 0, 2 * E_ * sizeof(float), stream);

    k_wcomb<<<256, 256, 0, stream>>>(Wg, Wc, wcomb64, wcomb32);
    k_hcond<<<1024, 256, 0, stream>>>(cond, Wc, hcond64);
    k_lbias<<<64, 256, 0, stream>>>(hcond64, Wg, lbias64, lbias32);
    k_main<<<NTOK / MT, 256, 0, stream>>>(x, wcomb32, lbias32, out, ref_cnt, ref_list);
    k_refine<<<64, 256, 0, stream>>>(x, wcomb64, lbias64, ref_cnt, ref_list, out);
}